// Round 6
// baseline (266.433 us; speedup 1.0000x reference)
//
#include <hip/hip_runtime.h>
#include <hip/hip_bf16.h>

// Inputs q,k,v are FLOAT32; output FLOAT32 (confirmed R2/R7).

#define H_  16
#define L_  8192
#define D_  64
#define MB_ 128   // query blocks (L/64)
#define NB_ 128   // kv blocks
#define TK_ 16    // top-k kv blocks per query block
#define ST_ 72    // LDS row stride for phase-1 v transpose tile

typedef __bf16 bf16x8 __attribute__((ext_vector_type(8)));
typedef __bf16 bf16x4 __attribute__((ext_vector_type(4)));
typedef short  s16x4  __attribute__((ext_vector_type(4)));
typedef float  f32x4  __attribute__((ext_vector_type(4)));
typedef unsigned short u16x8 __attribute__((ext_vector_type(8)));

union BFU { __hip_bfloat16 h; unsigned short u; };

static __device__ inline unsigned short f2bfu(float f) {
  BFU c; c.h = __float2bfloat16(f); return c.u;
}

static __device__ inline f32x4 mfma16(bf16x4 a, bf16x4 b, f32x4 c) {
#if __has_builtin(__builtin_amdgcn_mfma_f32_16x16x16bf16_1k)
  return __builtin_amdgcn_mfma_f32_16x16x16bf16_1k(
      __builtin_bit_cast(s16x4, a), __builtin_bit_cast(s16x4, b), c, 0, 0, 0);
#elif __has_builtin(__builtin_amdgcn_mfma_f32_16x16x16_bf16)
  return __builtin_amdgcn_mfma_f32_16x16x16_bf16(a, b, c, 0, 0, 0);
#else
  f32x4 d = c;
  asm("v_mfma_f32_16x16x16_bf16 %0, %1, %2, %0" : "+v"(d) : "v"(a), "v"(b));
  return d;
#endif
}

// module-scope scratch (round-3 lesson: never trust d_ws for the lut)
__device__ unsigned short g_qb[(size_t)H_ * L_ * D_];   // q * (sm_scale*log2e) as bf16
__device__ unsigned short g_kb[(size_t)H_ * L_ * D_];   // k as bf16
__device__ unsigned short g_vt[(size_t)H_ * D_ * L_];   // v TRANSPOSED bf16: [h][d][kk]
__device__ float g_qpool[H_ * NB_ * 64];
__device__ float g_kpool[H_ * NB_ * 64];
__device__ int   g_lut[H_ * MB_ * TK_];

static __device__ inline void cvt8_2(const float4& f0, const float4& f1,
                                     unsigned short* dst) {
  u16x8 s;
  s[0] = f2bfu(f0.x); s[1] = f2bfu(f0.y); s[2] = f2bfu(f0.z); s[3] = f2bfu(f0.w);
  s[4] = f2bfu(f1.x); s[5] = f2bfu(f1.y); s[6] = f2bfu(f1.z); s[7] = f2bfu(f1.w);
  *(u16x8*)dst = s;
}

static __device__ inline void cvt8_2s(const float4& f0, const float4& f1,
                                      unsigned short* dst, float sc) {
  u16x8 s;
  s[0] = f2bfu(f0.x * sc); s[1] = f2bfu(f0.y * sc);
  s[2] = f2bfu(f0.z * sc); s[3] = f2bfu(f0.w * sc);
  s[4] = f2bfu(f1.x * sc); s[5] = f2bfu(f1.y * sc);
  s[6] = f2bfu(f1.z * sc); s[7] = f2bfu(f1.w * sc);
  *(u16x8*)dst = s;
}

// -------- phase 1: fused f32->bf16 convert (q,k) + V transpose + pooling --
__global__ __launch_bounds__(256)
void fusedpool_kernel(const float* __restrict__ q,
                      const float* __restrict__ k,
                      const float* __restrict__ v) {
  __shared__ float qt[64 * 64];
  __shared__ float kt[64 * 64];
  __shared__ __align__(16) unsigned short vt_s[64 * ST_];  // bf16 v tile [kk][d]
  __shared__ float pq[4][64], pk[4][64];

  const int b = blockIdx.x;           // h*NB_ + n
  const int h = b >> 7, n = b & 127;
  const int t = threadIdx.x;
  const int r = t >> 2, c = (t & 3) * 16;
  const size_t base = (size_t)b * 4096 + r * 64 + c;
  const float cs = 0.18033688011112042f;  // (1/sqrt(64)) * log2(e), baked into Q

  float4 qf0 = *(const float4*)(q + base),      qf1 = *(const float4*)(q + base + 4);
  float4 qf2 = *(const float4*)(q + base + 8),  qf3 = *(const float4*)(q + base + 12);
  float4 kf0 = *(const float4*)(k + base),      kf1 = *(const float4*)(k + base + 4);
  float4 kf2 = *(const float4*)(k + base + 8),  kf3 = *(const float4*)(k + base + 12);
  float4 vf0 = *(const float4*)(v + base),      vf1 = *(const float4*)(v + base + 4);
  float4 vf2 = *(const float4*)(v + base + 8),  vf3 = *(const float4*)(v + base + 12);

  // scaled Q, plain K straight to global bf16
  cvt8_2s(qf0, qf1, g_qb + base, cs);  cvt8_2s(qf2, qf3, g_qb + base + 8, cs);
  cvt8_2(kf0, kf1, g_kb + base);       cvt8_2(kf2, kf3, g_kb + base + 8);
  // V bf16 into LDS for transpose (row=kk, col=d; 144B stride keeps 16B align)
  cvt8_2(vf0, vf1, vt_s + r * ST_ + c);
  cvt8_2(vf2, vf3, vt_s + r * ST_ + c + 8);

  // stash f32 q,k tiles for exact pooling (unscaled: lut must match reference)
  *(float4*)(qt + r * 64 + c)      = qf0; *(float4*)(qt + r * 64 + c + 4)  = qf1;
  *(float4*)(qt + r * 64 + c + 8)  = qf2; *(float4*)(qt + r * 64 + c + 12) = qf3;
  *(float4*)(kt + r * 64 + c)      = kf0; *(float4*)(kt + r * 64 + c + 4)  = kf1;
  *(float4*)(kt + r * 64 + c + 8)  = kf2; *(float4*)(kt + r * 64 + c + 12) = kf3;
  __syncthreads();

  const int col = t & 63, g = t >> 6;
  float sq = 0.f, sk = 0.f;
  for (int rr = g * 16; rr < g * 16 + 16; ++rr) {
    sq += qt[rr * 64 + col];
    sk += kt[rr * 64 + col];
  }
  pq[g][col] = sq; pk[g][col] = sk;

  // transposed V out: thread owns d=t>>2, kk = c..c+15 of this block
  u16x8 va, vb;
  #pragma unroll
  for (int i = 0; i < 8; ++i) va[i] = vt_s[(c + i) * ST_ + r];
  #pragma unroll
  for (int i = 0; i < 8; ++i) vb[i] = vt_s[(c + 8 + i) * ST_ + r];
  const size_t vo = ((size_t)h * 64 + r) * (size_t)L_ + (size_t)n * 64 + c;
  *(u16x8*)(g_vt + vo)     = va;
  *(u16x8*)(g_vt + vo + 8) = vb;

  __syncthreads();
  if (t < 64) {
    g_qpool[b * 64 + t] = (pq[0][t] + pq[1][t] + pq[2][t] + pq[3][t]) * (1.f / 64.f);
    g_kpool[b * 64 + t] = (pk[0][t] + pk[1][t] + pk[2][t] + pk[3][t]) * (1.f / 64.f);
  }
}

// NOTE: center_kernel deleted (rank-preserving per-row shift; R3-verified).

// -------- phase 1c: pred = qpool . kpool^T, top-16 per row ---------------
__global__ void topk_kernel() {
  const int b = blockIdx.x;           // h*MB_ + m
  const int h = b >> 7;
  const int lane = threadIdx.x;       // 0..63; handles n=lane and n=lane+64
  const float4* qrow = (const float4*)(g_qpool + b * 64);
  const float4* k0 = (const float4*)(g_kpool + (h * NB_ + lane) * 64);
  const float4* k1 = (const float4*)(g_kpool + (h * NB_ + lane + 64) * 64);
  float v0 = 0.f, v1 = 0.f;
  for (int i = 0; i < 16; ++i) {
    float4 qv = qrow[i];
    float4 a = k0[i];
    float4 c = k1[i];
    v0 += qv.x * a.x + qv.y * a.y + qv.z * a.z + qv.w * a.w;
    v1 += qv.x * c.x + qv.y * c.y + qv.z * c.z + qv.w * c.w;
  }
  // iterative argmax, ties -> lower index (matches jax.lax.top_k set)
  for (int t = 0; t < TK_; ++t) {
    float bv; int bi;
    if (v0 >= v1) { bv = v0; bi = lane; } else { bv = v1; bi = lane + 64; }
    for (int mask = 1; mask < 64; mask <<= 1) {
      float ov = __shfl_xor(bv, mask, 64);
      int   oi = __shfl_xor(bi, mask, 64);
      if (ov > bv || (ov == bv && oi < bi)) { bv = ov; bi = oi; }
    }
    if (lane == 0) g_lut[b * TK_ + t] = bi;
    if (bi == lane) v0 = -3.0e38f;
    else if (bi == lane + 64) v1 = -3.0e38f;
  }
}

// -------- phase 2: sparse flash attention, KV-SPLIT across waves ---------
// Wave w owns kv rows [16w,16w+16) of every KV block, for ALL 64 q rows
// (Q in registers). Fragments load DIRECT from global — disjoint across
// waves (1x traffic, unlike R2's 4x duplication), so NO LDS staging and
// NO barriers in the main loop. The swapped-S accumulator layout
// acc[g][r] = S[q=16g+l16][kv=16w+4*quad+r] is exactly the B-operand of
// v_mfma_f32_16x16x16_bf16 (k=quad*4+j), so PV needs no P relayout at all.
// Cost: per-wave O^T partials (64 VGPRs) + one-time LDS reduce epilogue.
__global__ __launch_bounds__(256, 3)
void attn_kernel(float* __restrict__ out) {
  __shared__ float LDSo[4][16][65];   // per-wave O^T slice, per d-chunk
  __shared__ float LDSr[4][64];       // per-wave partial rowsums

  const int blk = blockIdx.x;
  // XCD swizzle: h = blk&15 -> blk%8 == h%8; 2 heads/XCD, K+V bf16 = 4 MB = L2
  const int h = blk & 15, m = blk >> 4;
  const int t = threadIdx.x;
  const int w = t >> 6;                // wave id: kv rows 16w..16w+15
  const int lane = t & 63;
  const int l16 = lane & 15, quad = lane >> 4;

  // Q in registers: B[n=q-in-group=l16][k=quad*8+j], 4 groups x 2 halves
  const unsigned short* qg = g_qb + ((size_t)h * L_ + (size_t)m * 64) * D_;
  bf16x8 qb0[4], qb1[4];
  #pragma unroll
  for (int g = 0; g < 4; ++g) {
    const unsigned short* qp = qg + (16 * g + l16) * 64 + quad * 8;
    qb0[g] = *(const bf16x8*)(qp);
    qb1[g] = *(const bf16x8*)(qp + 32);
  }

  f32x4 o[4][4];                       // o[n4][g] = O^T[16n4+4q+r][16g+l16]
  #pragma unroll
  for (int n4 = 0; n4 < 4; ++n4)
    #pragma unroll
    for (int g = 0; g < 4; ++g) o[n4][g] = (f32x4){0.f, 0.f, 0.f, 0.f};
  float lsum[4] = {0.f, 0.f, 0.f, 0.f};

  const int* my_lut = g_lut + (h * MB_ + m) * TK_;
  const unsigned short* kh = g_kb + (size_t)h * L_ * D_;
  const unsigned short* vg = g_vt + (size_t)h * D_ * L_;
  const int krow = (16 * w + l16) * 64 + quad * 8;  // K frag offset in block
  const int vcol = 16 * w + quad * 4;               // V^T frag col offset

  // fragment double-buffers (compile-time indexed after full unroll)
  bf16x8 ka0[2], ka1[2];
  bf16x4 va[2][4];

  // prologue: load KV block 0 fragments
  {
    const int kb0 = __builtin_amdgcn_readfirstlane(my_lut[0]);
    const unsigned short* kbp = kh + (size_t)kb0 * 4096 + krow;
    ka0[0] = *(const bf16x8*)(kbp);
    ka1[0] = *(const bf16x8*)(kbp + 32);
    const unsigned short* vbp = vg + (size_t)kb0 * 64 + vcol;
    #pragma unroll
    for (int n4 = 0; n4 < 4; ++n4)
      va[0][n4] = *(const bf16x4*)(vbp + (size_t)(16 * n4 + l16) * L_);
  }

  #pragma unroll
  for (int j = 0; j < TK_; ++j) {
    const int cb = j & 1, nb = cb ^ 1;
    // issue next block's fragment loads (latency hides under compute)
    if (j + 1 < TK_) {
      const int kbn = __builtin_amdgcn_readfirstlane(my_lut[j + 1]);
      const unsigned short* kbp = kh + (size_t)kbn * 4096 + krow;
      ka0[nb] = *(const bf16x8*)(kbp);
      ka1[nb] = *(const bf16x8*)(kbp + 32);
      const unsigned short* vbp = vg + (size_t)kbn * 64 + vcol;
      #pragma unroll
      for (int n4 = 0; n4 < 4; ++n4)
        va[nb][n4] = *(const bf16x4*)(vbp + (size_t)(16 * n4 + l16) * L_);
    }

    // ---- S = K Q^T : acc[g][r] = S[q=16g+l16][kv=16w+4quad+r] ------------
    f32x4 acc[4];
    __builtin_amdgcn_s_setprio(1);
    #pragma unroll
    for (int g = 0; g < 4; ++g) {
      f32x4 z = (f32x4){0.f, 0.f, 0.f, 0.f};
      z = __builtin_amdgcn_mfma_f32_16x16x32_bf16(ka0[cb], qb0[g], z, 0, 0, 0);
      z = __builtin_amdgcn_mfma_f32_16x16x32_bf16(ka1[cb], qb1[g], z, 0, 0, 0);
      acc[g] = z;
    }
    __builtin_amdgcn_s_setprio(0);

    // ---- no-max softmax (pre-scaled log2 units) + in-lane pack -----------
    bf16x4 pb[4];
    #pragma unroll
    for (int g = 0; g < 4; ++g) {
      const float p0 = exp2f(acc[g][0]), p1 = exp2f(acc[g][1]);
      const float p2 = exp2f(acc[g][2]), p3 = exp2f(acc[g][3]);
      lsum[g] += (p0 + p1) + (p2 + p3);
      unsigned int d0, d1;
      asm("v_cvt_pk_bf16_f32 %0, %1, %2" : "=v"(d0) : "v"(p0), "v"(p1));
      asm("v_cvt_pk_bf16_f32 %0, %1, %2" : "=v"(d1) : "v"(p2), "v"(p3));
      uint2 dd; dd.x = d0; dd.y = d1;
      pb[g] = __builtin_bit_cast(bf16x4, dd);
    }

    // ---- O^T += V^T P^T : 16x16x16, B=pb straight from registers ---------
    __builtin_amdgcn_s_setprio(1);
    #pragma unroll
    for (int n4 = 0; n4 < 4; ++n4)
      #pragma unroll
      for (int g = 0; g < 4; ++g)
        o[n4][g] = mfma16(va[cb][n4], pb[g], o[n4][g]);
    __builtin_amdgcn_s_setprio(0);
  }

  // ---- epilogue: cross-wave reduce (one-time) ----------------------------
  // rowsum: reduce over quads (kv within slice), publish per-wave partial
  #pragma unroll
  for (int g = 0; g < 4; ++g) {
    float rs = lsum[g];
    rs += __shfl_xor(rs, 16, 64);
    rs += __shfl_xor(rs, 32, 64);
    lsum[g] = rs;                      // uniform across quads
  }
  if (quad == 0) {
    #pragma unroll
    for (int g = 0; g < 4; ++g) LDSr[w][16 * g + l16] = lsum[g];
  }
  __syncthreads();

  const int dr = t & 15, q0 = (t >> 4) * 4;
  float rinv[4];
  #pragma unroll
  for (int qq = 0; qq < 4; ++qq)
    rinv[qq] = 1.0f / (LDSr[0][q0 + qq] + LDSr[1][q0 + qq] +
                       LDSr[2][q0 + qq] + LDSr[3][q0 + qq]);

  const size_t obase = ((size_t)h * L_ + (size_t)m * 64) * D_;
  #pragma unroll
  for (int n4 = 0; n4 < 4; ++n4) {
    // publish this wave's O^T d-chunk
    #pragma unroll
    for (int g = 0; g < 4; ++g)
      #pragma unroll
      for (int r = 0; r < 4; ++r)
        LDSo[w][quad * 4 + r][16 * g + l16] = o[n4][g][r];
    __syncthreads();
    // sum 4 waves, normalize, store (coalesced 64B runs along d)
    #pragma unroll
    for (int qq = 0; qq < 4; ++qq) {
      const int qv = q0 + qq;
      const float s = LDSo[0][dr][qv] + LDSo[1][dr][qv] +
                      LDSo[2][dr][qv] + LDSo[3][dr][qv];
      out[obase + (size_t)qv * 64 + n4 * 16 + dr] = s * rinv[qq];
    }
    __syncthreads();
  }
}

extern "C" void kernel_launch(void* const* d_in, const int* in_sizes, int n_in,
                              void* d_out, int out_size, void* d_ws, size_t ws_size,
                              hipStream_t stream) {
  const float* q = (const float*)d_in[0];
  const float* k = (const float*)d_in[1];
  const float* v = (const float*)d_in[2];
  float* out = (float*)d_out;

  fusedpool_kernel<<<H_ * NB_, 256, 0, stream>>>(q, k, v);
  topk_kernel<<<H_ * MB_, 64, 0, stream>>>();
  attn_kernel<<<H_ * MB_, 256, 0, stream>>>(out);
}

// Round 7
// 221.509 us; speedup vs baseline: 1.2028x; 1.2028x over previous
//
#include <hip/hip_runtime.h>
#include <hip/hip_bf16.h>

// Inputs q,k,v are FLOAT32; output FLOAT32 (confirmed R2/R7).

#define H_  16
#define L_  8192
#define D_  64
#define MB_ 128   // query blocks (L/64)
#define NB_ 128   // kv blocks
#define TK_ 16    // top-k kv blocks per query block
#define ST_ 72    // LDS row stride for phase-1 v transpose tile

typedef __bf16 bf16x8 __attribute__((ext_vector_type(8)));
typedef __bf16 bf16x4 __attribute__((ext_vector_type(4)));
typedef short  s16x4  __attribute__((ext_vector_type(4)));
typedef float  f32x4  __attribute__((ext_vector_type(4)));
typedef unsigned short u16x8 __attribute__((ext_vector_type(8)));

union BFU { __hip_bfloat16 h; unsigned short u; };

static __device__ inline unsigned short f2bfu(float f) {
  BFU c; c.h = __float2bfloat16(f); return c.u;
}

static __device__ inline f32x4 mfma16(bf16x4 a, bf16x4 b, f32x4 c) {
#if __has_builtin(__builtin_amdgcn_mfma_f32_16x16x16bf16_1k)
  return __builtin_amdgcn_mfma_f32_16x16x16bf16_1k(
      __builtin_bit_cast(s16x4, a), __builtin_bit_cast(s16x4, b), c, 0, 0, 0);
#elif __has_builtin(__builtin_amdgcn_mfma_f32_16x16x16_bf16)
  return __builtin_amdgcn_mfma_f32_16x16x16_bf16(a, b, c, 0, 0, 0);
#else
  f32x4 d = c;
  asm("v_mfma_f32_16x16x16_bf16 %0, %1, %2, %0" : "+v"(d) : "v"(a), "v"(b));
  return d;
#endif
}

static __device__ inline bf16x4 lo4(bf16x8 v) {
  return __builtin_shufflevector(v, v, 0, 1, 2, 3);
}
static __device__ inline bf16x4 hi4(bf16x8 v) {
  return __builtin_shufflevector(v, v, 4, 5, 6, 7);
}

// module-scope scratch (round-3 lesson: never trust d_ws for the lut)
__device__ unsigned short g_qb[(size_t)H_ * L_ * D_];  // q*(sm_scale*log2e), row-major bf16
// K in MFMA-FRAGMENT order: [h][n][w][half][lane=quad*16+l16][8]
//   frag elem: K[16w+l16][32*half + quad*8 + i]
__device__ unsigned short g_kf[(size_t)H_ * NB_ * 4096];
// V^T in MFMA-FRAGMENT order: [h][n][w][lane][n4][4]
//   frag elem: V[16w + quad*4 + r][16*n4 + l16]  (= V^T[d][kv])
__device__ unsigned short g_vf[(size_t)H_ * NB_ * 4096];
__device__ float g_qpool[H_ * NB_ * 64];
__device__ float g_kpool[H_ * NB_ * 64];
__device__ int   g_lut[H_ * MB_ * TK_];

static __device__ inline void cvt8_2(const float4& f0, const float4& f1,
                                     unsigned short* dst) {
  u16x8 s;
  s[0] = f2bfu(f0.x); s[1] = f2bfu(f0.y); s[2] = f2bfu(f0.z); s[3] = f2bfu(f0.w);
  s[4] = f2bfu(f1.x); s[5] = f2bfu(f1.y); s[6] = f2bfu(f1.z); s[7] = f2bfu(f1.w);
  *(u16x8*)dst = s;
}

static __device__ inline void cvt8_2s(const float4& f0, const float4& f1,
                                      unsigned short* dst, float sc) {
  u16x8 s;
  s[0] = f2bfu(f0.x * sc); s[1] = f2bfu(f0.y * sc);
  s[2] = f2bfu(f0.z * sc); s[3] = f2bfu(f0.w * sc);
  s[4] = f2bfu(f1.x * sc); s[5] = f2bfu(f1.y * sc);
  s[6] = f2bfu(f1.z * sc); s[7] = f2bfu(f1.w * sc);
  *(u16x8*)dst = s;
}

// -------- phase 1: f32->bf16 convert + FRAGMENT-ORDER K/V + pooling ------
__global__ __launch_bounds__(256)
void fusedpool_kernel(const float* __restrict__ q,
                      const float* __restrict__ k,
                      const float* __restrict__ v) {
  __shared__ float qt[64 * 64];
  __shared__ float kt[64 * 64];
  __shared__ __align__(16) unsigned short vt_s[64 * ST_];  // bf16 v tile [kk][d]
  __shared__ float pq[4][64], pk[4][64];

  const int b = blockIdx.x;           // h*NB_ + n
  const int t = threadIdx.x;
  const int r = t >> 2, c = (t & 3) * 16;
  const size_t base = (size_t)b * 4096 + r * 64 + c;
  const float cs = 0.18033688011112042f;  // (1/sqrt(64)) * log2(e), baked into Q

  float4 qf0 = *(const float4*)(q + base),      qf1 = *(const float4*)(q + base + 4);
  float4 qf2 = *(const float4*)(q + base + 8),  qf3 = *(const float4*)(q + base + 12);
  float4 kf0 = *(const float4*)(k + base),      kf1 = *(const float4*)(k + base + 4);
  float4 kf2 = *(const float4*)(k + base + 8),  kf3 = *(const float4*)(k + base + 12);
  float4 vf0 = *(const float4*)(v + base),      vf1 = *(const float4*)(v + base + 4);
  float4 vf2 = *(const float4*)(v + base + 8),  vf3 = *(const float4*)(v + base + 12);

  // scaled Q straight to global bf16 (row-major)
  cvt8_2s(qf0, qf1, g_qb + base, cs);  cvt8_2s(qf2, qf3, g_qb + base + 8, cs);

  // K straight from registers into FRAGMENT order:
  // this thread holds row r, cols [c,c+16) = half hf=c>>5, quads quadA,quadA+1
  {
    const int w_k = r >> 4, l16k = r & 15;
    const int hf = c >> 5, quadA = (c & 31) >> 3;
    unsigned short* kfp = g_kf + ((size_t)b * 4 + w_k) * 1024 + hf * 512 + l16k * 8;
    cvt8_2(kf0, kf1, kfp + quadA * 128);
    cvt8_2(kf2, kf3, kfp + (quadA + 1) * 128);
  }

  // V bf16 into LDS for transpose (row=kk, col=d; 144B stride keeps 16B align)
  cvt8_2(vf0, vf1, vt_s + r * ST_ + c);
  cvt8_2(vf2, vf3, vt_s + r * ST_ + c + 8);

  // stash f32 q,k tiles for exact pooling (unscaled: lut must match reference)
  *(float4*)(qt + r * 64 + c)      = qf0; *(float4*)(qt + r * 64 + c + 4)  = qf1;
  *(float4*)(qt + r * 64 + c + 8)  = qf2; *(float4*)(qt + r * 64 + c + 12) = qf3;
  *(float4*)(kt + r * 64 + c)      = kf0; *(float4*)(kt + r * 64 + c + 4)  = kf1;
  *(float4*)(kt + r * 64 + c + 8)  = kf2; *(float4*)(kt + r * 64 + c + 12) = kf3;
  __syncthreads();

  const int col = t & 63, g = t >> 6;
  float sq = 0.f, sk = 0.f;
  for (int rr = g * 16; rr < g * 16 + 16; ++rr) {
    sq += qt[rr * 64 + col];
    sk += kt[rr * 64 + col];
  }
  pq[g][col] = sq; pk[g][col] = sk;

  // V into FRAGMENT order: thread t = (wave-slice wv, lane lv)
  // frag[lv][n4*4+rr] = V[16wv + quadv*4 + rr][16n4 + l16v]
  {
    const int wv = t >> 6, lv = t & 63;
    const int l16v = lv & 15, quadv = lv >> 4;
    u16x8 f0, f1;
    #pragma unroll
    for (int n4 = 0; n4 < 2; ++n4)
      #pragma unroll
      for (int rr = 0; rr < 4; ++rr)
        f0[n4 * 4 + rr] = vt_s[(16 * wv + quadv * 4 + rr) * ST_ + 16 * n4 + l16v];
    #pragma unroll
    for (int n4 = 2; n4 < 4; ++n4)
      #pragma unroll
      for (int rr = 0; rr < 4; ++rr)
        f1[(n4 - 2) * 4 + rr] = vt_s[(16 * wv + quadv * 4 + rr) * ST_ + 16 * n4 + l16v];
    unsigned short* vfp = g_vf + ((size_t)b * 4 + wv) * 1024 + lv * 16;
    *(u16x8*)(vfp)     = f0;
    *(u16x8*)(vfp + 8) = f1;
  }

  __syncthreads();
  if (t < 64) {
    g_qpool[b * 64 + t] = (pq[0][t] + pq[1][t] + pq[2][t] + pq[3][t]) * (1.f / 64.f);
    g_kpool[b * 64 + t] = (pk[0][t] + pk[1][t] + pk[2][t] + pk[3][t]) * (1.f / 64.f);
  }
}

// NOTE: center_kernel deleted (rank-preserving per-row shift; R3-verified).

// -------- phase 1c: pred = qpool . kpool^T, top-16 per row ---------------
__global__ void topk_kernel() {
  const int b = blockIdx.x;           // h*MB_ + m
  const int h = b >> 7;
  const int lane = threadIdx.x;       // 0..63; handles n=lane and n=lane+64
  const float4* qrow = (const float4*)(g_qpool + b * 64);
  const float4* k0 = (const float4*)(g_kpool + (h * NB_ + lane) * 64);
  const float4* k1 = (const float4*)(g_kpool + (h * NB_ + lane + 64) * 64);
  float v0 = 0.f, v1 = 0.f;
  for (int i = 0; i < 16; ++i) {
    float4 qv = qrow[i];
    float4 a = k0[i];
    float4 c = k1[i];
    v0 += qv.x * a.x + qv.y * a.y + qv.z * a.z + qv.w * a.w;
    v1 += qv.x * c.x + qv.y * c.y + qv.z * c.z + qv.w * c.w;
  }
  // iterative argmax, ties -> lower index (matches jax.lax.top_k set)
  for (int t = 0; t < TK_; ++t) {
    float bv; int bi;
    if (v0 >= v1) { bv = v0; bi = lane; } else { bv = v1; bi = lane + 64; }
    for (int mask = 1; mask < 64; mask <<= 1) {
      float ov = __shfl_xor(bv, mask, 64);
      int   oi = __shfl_xor(bi, mask, 64);
      if (ov > bv || (ov == bv && oi < bi)) { bv = ov; bi = oi; }
    }
    if (lane == 0) g_lut[b * TK_ + t] = bi;
    if (bi == lane) v0 = -3.0e38f;
    else if (bi == lane + 64) v1 = -3.0e38f;
  }
}

// -------- phase 2: sparse flash attention, KV-split + FRAGMENT loads -----
// Wave w owns kv rows [16w,16w+16) for ALL 64 q (Q in registers). K and V
// were pre-permuted into fragment order by phase 1, so every main-loop load
// is a coalesced burst: K = 2x 1KB (lane*16B), V = 2x 16B/lane @32B stride.
// ZERO LDS ops and ZERO barriers in the main loop (R6 structure, coalesced).
// Head mapping keeps ~1 active head (3MB frags) per XCD-L2 (4MB).
__global__ __launch_bounds__(256, 3)
void attn_kernel(float* __restrict__ out) {
  __shared__ float LDSo[4][16][65];   // per-wave O^T slice, per d-chunk
  __shared__ float LDSr[4][64];       // per-wave partial rowsums

  const int flat = blockIdx.x;
  // bijective: xcd = flat&7 -> heads 2*xcd, 2*xcd+1 live on one XCD,
  // and each XCD runs one head's 128 blocks before the other.
  const int h = (flat & 7) * 2 + ((flat >> 10) & 1);
  const int m = (flat >> 3) & 127;
  const int t = threadIdx.x;
  const int w = t >> 6;                // wave id: kv rows 16w..16w+15
  const int lane = t & 63;
  const int l16 = lane & 15, quad = lane >> 4;

  // Q in registers: B[n=q-in-group=l16][k=quad*8+j], 4 groups x 2 halves
  const unsigned short* qg = g_qb + ((size_t)h * L_ + (size_t)m * 64) * D_;
  bf16x8 qb0[4], qb1[4];
  #pragma unroll
  for (int g = 0; g < 4; ++g) {
    const unsigned short* qp = qg + (16 * g + l16) * 64 + quad * 8;
    qb0[g] = *(const bf16x8*)(qp);
    qb1[g] = *(const bf16x8*)(qp + 32);
  }

  f32x4 o[4][4];                       // o[n4][g] = O^T[16n4+...][16g+l16]
  #pragma unroll
  for (int n4 = 0; n4 < 4; ++n4)
    #pragma unroll
    for (int g = 0; g < 4; ++g) o[n4][g] = (f32x4){0.f, 0.f, 0.f, 0.f};
  float lsum[4] = {0.f, 0.f, 0.f, 0.f};

  const int* my_lut = g_lut + (h * MB_ + m) * TK_;

  // fragment double-buffers (compile-time indexed after full unroll)
  bf16x8 ka0[2], ka1[2], vv01[2], vv23[2];

  // prologue: load KV block 0 fragments (coalesced bursts)
  {
    const int kb0 = __builtin_amdgcn_readfirstlane(my_lut[0]);
    const unsigned short* kbp = g_kf + ((size_t)(h * NB_ + kb0) * 4 + w) * 1024;
    ka0[0] = *(const bf16x8*)(kbp + lane * 8);
    ka1[0] = *(const bf16x8*)(kbp + 512 + lane * 8);
    const unsigned short* vbp = g_vf + ((size_t)(h * NB_ + kb0) * 4 + w) * 1024 + lane * 16;
    vv01[0] = *(const bf16x8*)(vbp);
    vv23[0] = *(const bf16x8*)(vbp + 8);
  }

  #pragma unroll
  for (int j = 0; j < TK_; ++j) {
    const int cb = j & 1, nb = cb ^ 1;
    // issue next block's fragment loads (latency hides under compute)
    if (j + 1 < TK_) {
      const int kbn = __builtin_amdgcn_readfirstlane(my_lut[j + 1]);
      const unsigned short* kbp = g_kf + ((size_t)(h * NB_ + kbn) * 4 + w) * 1024;
      ka0[nb] = *(const bf16x8*)(kbp + lane * 8);
      ka1[nb] = *(const bf16x8*)(kbp + 512 + lane * 8);
      const unsigned short* vbp = g_vf + ((size_t)(h * NB_ + kbn) * 4 + w) * 1024 + lane * 16;
      vv01[nb] = *(const bf16x8*)(vbp);
      vv23[nb] = *(const bf16x8*)(vbp + 8);
    }

    // ---- S = K Q^T : acc[g][r] = S[q=16g+l16][kv=16w+4quad+r] ------------
    f32x4 acc[4];
    __builtin_amdgcn_s_setprio(1);
    #pragma unroll
    for (int g = 0; g < 4; ++g) {
      f32x4 z = (f32x4){0.f, 0.f, 0.f, 0.f};
      z = __builtin_amdgcn_mfma_f32_16x16x32_bf16(ka0[cb], qb0[g], z, 0, 0, 0);
      z = __builtin_amdgcn_mfma_f32_16x16x32_bf16(ka1[cb], qb1[g], z, 0, 0, 0);
      acc[g] = z;
    }
    __builtin_amdgcn_s_setprio(0);

    // ---- no-max softmax (pre-scaled log2 units) + in-lane pack -----------
    bf16x4 pb[4];
    #pragma unroll
    for (int g = 0; g < 4; ++g) {
      const float p0 = exp2f(acc[g][0]), p1 = exp2f(acc[g][1]);
      const float p2 = exp2f(acc[g][2]), p3 = exp2f(acc[g][3]);
      lsum[g] += (p0 + p1) + (p2 + p3);
      unsigned int d0, d1;
      asm("v_cvt_pk_bf16_f32 %0, %1, %2" : "=v"(d0) : "v"(p0), "v"(p1));
      asm("v_cvt_pk_bf16_f32 %0, %1, %2" : "=v"(d1) : "v"(p2), "v"(p3));
      uint2 dd; dd.x = d0; dd.y = d1;
      pb[g] = __builtin_bit_cast(bf16x4, dd);
    }

    // ---- O^T += V^T P^T : 16x16x16, A and B straight from registers ------
    const bf16x4 va_[4] = { lo4(vv01[cb]), hi4(vv01[cb]),
                            lo4(vv23[cb]), hi4(vv23[cb]) };
    __builtin_amdgcn_s_setprio(1);
    #pragma unroll
    for (int n4 = 0; n4 < 4; ++n4)
      #pragma unroll
      for (int g = 0; g < 4; ++g)
        o[n4][g] = mfma16(va_[n4], pb[g], o[n4][g]);
    __builtin_amdgcn_s_setprio(0);
  }

  // ---- epilogue: cross-wave reduce (one-time) ----------------------------
  #pragma unroll
  for (int g = 0; g < 4; ++g) {
    float rs = lsum[g];
    rs += __shfl_xor(rs, 16, 64);
    rs += __shfl_xor(rs, 32, 64);
    lsum[g] = rs;                      // uniform across quads
  }
  if (quad == 0) {
    #pragma unroll
    for (int g = 0; g < 4; ++g) LDSr[w][16 * g + l16] = lsum[g];
  }
  __syncthreads();

  const int dr = t & 15, q0 = (t >> 4) * 4;
  float rinv[4];
  #pragma unroll
  for (int qq = 0; qq < 4; ++qq)
    rinv[qq] = 1.0f / (LDSr[0][q0 + qq] + LDSr[1][q0 + qq] +
                       LDSr[2][q0 + qq] + LDSr[3][q0 + qq]);

  const size_t obase = ((size_t)h * L_ + (size_t)m * 64) * D_;
  #pragma unroll
  for (int n4 = 0; n4 < 4; ++n4) {
    // publish this wave's O^T d-chunk
    #pragma unroll
    for (int g = 0; g < 4; ++g)
      #pragma unroll
      for (int r = 0; r < 4; ++r)
        LDSo[w][quad * 4 + r][16 * g + l16] = o[n4][g][r];
    __syncthreads();
    // sum 4 waves, normalize, store (coalesced 64B runs along d)
    #pragma unroll
    for (int qq = 0; qq < 4; ++qq) {
      const int qv = q0 + qq;
      const float s = LDSo[0][dr][qv] + LDSo[1][dr][qv] +
                      LDSo[2][dr][qv] + LDSo[3][dr][qv];
      out[obase + (size_t)qv * 64 + n4 * 16 + dr] = s * rinv[qq];
    }
    __syncthreads();
  }
}

extern "C" void kernel_launch(void* const* d_in, const int* in_sizes, int n_in,
                              void* d_out, int out_size, void* d_ws, size_t ws_size,
                              hipStream_t stream) {
  const float* q = (const float*)d_in[0];
  const float* k = (const float*)d_in[1];
  const float* v = (const float*)d_in[2];
  float* out = (float*)d_out;

  fusedpool_kernel<<<H_ * NB_, 256, 0, stream>>>(q, k, v);
  topk_kernel<<<H_ * MB_, 64, 0, stream>>>();
  attn_kernel<<<H_ * MB_, 256, 0, stream>>>(out);
}